// Round 1
// 529.430 us; speedup vs baseline: 1.1248x; 1.1248x over previous
//
#include <hip/hip_runtime.h>
#include <math.h>

#define NN 100000
#define EE 1600000
#define D 128
#define NB 782            // buckets of 128 rows: ceil(100000/128)
#define SBLK 98           // scatter blocks
#define EPB 16384         // edges per scatter block (98*16384 >= EE)

typedef __attribute__((ext_vector_type(8))) short short8;
typedef __attribute__((ext_vector_type(4))) float floatx4;

// ---------- helpers ----------
static __device__ __forceinline__ unsigned short f2bf(float f) {
  unsigned int u = __builtin_bit_cast(unsigned int, f);
  u = (u + 0x7fff + ((u >> 16) & 1)) >> 16;   // RNE
  return (unsigned short)u;
}
static __device__ __forceinline__ unsigned int pk2(float a, float b) {
  return (unsigned int)f2bf(a) | ((unsigned int)f2bf(b) << 16);
}
static __device__ __forceinline__ float bflo(unsigned int u) { return __builtin_bit_cast(float, u << 16); }
static __device__ __forceinline__ float bfhi(unsigned int u) { return __builtin_bit_cast(float, u & 0xffff0000u); }
static __device__ __forceinline__ float bf2f(unsigned short s) {
  return __builtin_bit_cast(float, (unsigned int)s << 16);
}
static __device__ __forceinline__ float sig_f(float x) { return 1.f / (1.f + __expf(-x)); }
static __device__ __forceinline__ float tanh_f(float x) {
  float e = __expf(2.f * x);
  return 1.f - 2.f / (e + 1.f);
}

// ================= CSR build: bucket multisplit with single-owner writes =================

// Pass 1: per-(block,bucket) counts via LDS histogram
__global__ __launch_bounds__(1024) void b_count(const int* __restrict__ erow, int* __restrict__ cnt_pb) {
  __shared__ int s[NB];
  const int tid = threadIdx.x;
  for (int b = tid; b < NB; b += 1024) s[b] = 0;
  __syncthreads();
  const int base = blockIdx.x * EPB;
#pragma unroll
  for (int i = 0; i < 16; ++i) {
    int idx = base + i * 1024 + tid;
    if (idx < EE) atomicAdd(&s[erow[idx] >> 7], 1);
  }
  __syncthreads();
  for (int b = tid; b < NB; b += 1024) cnt_pb[blockIdx.x * NB + b] = s[b];
}

// Pass 2 (1 block): bucket totals -> exclusive bucket_off; per-(block,bucket) bases
__global__ __launch_bounds__(1024) void b_scan(const int* __restrict__ cnt_pb,
                                               int* __restrict__ base_pb, int* __restrict__ bucket_off) {
  __shared__ int s[1024];
  const int b = threadIdx.x;
  int tot = 0;
  if (b < NB) {
    for (int j = 0; j < SBLK; ++j) tot += cnt_pb[j * NB + b];
  }
  s[b] = tot;
  __syncthreads();
  for (int d = 1; d < 1024; d <<= 1) {
    int v = (b >= d) ? s[b - d] : 0;
    __syncthreads();
    s[b] += v;
    __syncthreads();
  }
  int excl = s[b] - tot;
  if (b < NB) {
    bucket_off[b] = excl;
    int run = excl;
    for (int j = 0; j < SBLK; ++j) { base_pb[j * NB + b] = run; run += cnt_pb[j * NB + b]; }
  }
  if (b == NB - 1) bucket_off[NB] = excl + tot;
}

// Pass 3: scatter into bucket arena; block writes per bucket are contiguous (write-combined)
__global__ __launch_bounds__(1024) void b_scatter(const int* __restrict__ erow, const int* __restrict__ ecol,
                                                  const float* __restrict__ ew,
                                                  const int* __restrict__ base_pb, int2* __restrict__ arena) {
  __shared__ int cur[NB];
  const int tid = threadIdx.x;
  for (int b = tid; b < NB; b += 1024) cur[b] = base_pb[blockIdx.x * NB + b];
  __syncthreads();
  const int base = blockIdx.x * EPB;
#pragma unroll
  for (int i = 0; i < 16; ++i) {
    int idx = base + i * 1024 + tid;
    if (idx < EE) {
      int r = erow[idx];
      int pos = atomicAdd(&cur[r >> 7], 1);
      int2 v;
      v.x = ecol[idx] | ((r & 127) << 24);   // col fits 17 bits; row-local 7 bits in 24..30
      v.y = __builtin_bit_cast(int, ew[idx]);
      arena[pos] = v;
    }
  }
}

// Pass 4: counting-sort within bucket -> final CSR (single-owner contiguous region) + row_start
__global__ __launch_bounds__(256) void b_sort(const int* __restrict__ bucket_off, const int2* __restrict__ arena,
                                              int2* __restrict__ edata, int* __restrict__ row_start) {
  __shared__ int rcnt[128];
  __shared__ int rcur[128];
  const int b = blockIdx.x;
  const int tid = threadIdx.x;
  const int lo = bucket_off[b], hi = bucket_off[b + 1];

  if (tid < 128) rcnt[tid] = 0;
  __syncthreads();
  for (int i = lo + tid; i < hi; i += 256) atomicAdd(&rcnt[(arena[i].x >> 24) & 127], 1);
  __syncthreads();
  int myc = (tid < 128) ? rcnt[tid] : 0;
  for (int d = 1; d < 128; d <<= 1) {
    int v = (tid < 128 && tid >= d) ? rcnt[tid - d] : 0;
    __syncthreads();
    if (tid < 128) rcnt[tid] += v;
    __syncthreads();
  }
  if (tid < 128) {
    int excl = rcnt[tid] - myc;
    rcur[tid] = lo + excl;
    int gr = b * 128 + tid;
    if (gr < NN) row_start[gr] = lo + excl;
  }
  if (b == NB - 1 && tid == 0) row_start[NN] = hi;
  __syncthreads();

  for (int i = lo + tid; i < hi; i += 256) {
    int2 v = arena[i];
    int rl = (v.x >> 24) & 127;
    int pos = atomicAdd(&rcur[rl], 1);
    int2 o;
    o.x = v.x & 0x00FFFFFF;
    o.y = v.y;
    edata[pos] = o;
  }
}

// ================= weight packing into MFMA B-fragment order =================
__global__ __launch_bounds__(64) void k_pack_zr(const float* __restrict__ ugW, const float* __restrict__ rgW,
                                                unsigned int* __restrict__ packZR) {
  int g = blockIdx.x;           // g = nt*8 + ks, nt 0..15, ks 0..7
  int nt = g >> 3, ks = g & 7;
  int lane = threadIdx.x;
  int o = nt * 16 + (lane & 15);
  int c0 = ks * 32 + (lane >> 4) * 8;
  const float* src = (o < 128 ? ugW + (size_t)o * 256 : rgW + (size_t)(o - 128) * 256) + c0;
  float4 f0 = ((const float4*)src)[0];
  float4 f1 = ((const float4*)src)[1];
  uint4 out;
  out.x = pk2(f0.x, f0.y);
  out.y = pk2(f0.z, f0.w);
  out.z = pk2(f1.x, f1.y);
  out.w = pk2(f1.z, f1.w);
  ((uint4*)packZR)[g * 64 + lane] = out;
}

__global__ __launch_bounds__(64) void k_pack_kn(const float* __restrict__ M, unsigned int* __restrict__ pack) {
  int g = blockIdx.x;           // g = nt*4 + ks, nt 0..7, ks 0..3
  int nt = g >> 2, ks = g & 3;
  int lane = threadIdx.x;
  int n = nt * 16 + (lane & 15);
  int k0 = ks * 32 + (lane >> 4) * 8;
  unsigned short v[8];
#pragma unroll
  for (int j = 0; j < 8; ++j) v[j] = f2bf(M[(size_t)(k0 + j) * 128 + n]);
  uint4 out;
  out.x = (unsigned int)v[0] | ((unsigned int)v[1] << 16);
  out.y = (unsigned int)v[2] | ((unsigned int)v[3] << 16);
  out.z = (unsigned int)v[4] | ((unsigned int)v[5] << 16);
  out.w = (unsigned int)v[6] | ((unsigned int)v[7] << 16);
  ((uint4*)pack)[g * 64 + lane] = out;
}

// ================= h0 = X @ W + b via MFMA (bf16 master) =================
__global__ __launch_bounds__(256) void init_mfma(
    const float* __restrict__ X, const short* __restrict__ packW, const float* __restrict__ bias,
    unsigned short* __restrict__ h_bf) {
  __shared__ __align__(16) short sX[32 * 136];
  const int tid = threadIdx.x;
  const int row0 = blockIdx.x * 32;

  {
    int r = tid >> 3, ch = tid & 7;
    const float4* px = (const float4*)(X + (size_t)(row0 + r) * D + ch * 16);
    float4 f0 = px[0], f1 = px[1], f2 = px[2], f3 = px[3];
    uint4 o0, o1;
    o0.x = pk2(f0.x, f0.y); o0.y = pk2(f0.z, f0.w);
    o0.z = pk2(f1.x, f1.y); o0.w = pk2(f1.z, f1.w);
    o1.x = pk2(f2.x, f2.y); o1.y = pk2(f2.z, f2.w);
    o1.z = pk2(f3.x, f3.y); o1.w = pk2(f3.z, f3.w);
    *(uint4*)(sX + r * 136 + ch * 16) = o0;
    *(uint4*)(sX + r * 136 + ch * 16 + 8) = o1;
  }
  __syncthreads();

  const int wave = tid >> 6, lane = tid & 63;
  const int quad = lane >> 4, l15 = lane & 15;
  const int mh = wave & 1, nh = wave >> 1;
  const int mrow = mh * 16 + l15;

  floatx4 acc[4];
  const floatx4 zero4 = {0.f, 0.f, 0.f, 0.f};
#pragma unroll
  for (int t = 0; t < 4; ++t) acc[t] = zero4;

  const short8* pW = (const short8*)packW;
#pragma unroll
  for (int ks = 0; ks < 4; ++ks) {
    short8 a = *(const short8*)(sX + mrow * 136 + ks * 32 + quad * 8);
#pragma unroll
    for (int t = 0; t < 4; ++t) {
      short8 b = pW[((nh * 4 + t) * 4 + ks) * 64 + lane];
      acc[t] = __builtin_amdgcn_mfma_f32_16x16x32_bf16(a, b, acc[t], 0, 0, 0);
    }
  }

#pragma unroll
  for (int t = 0; t < 4; ++t) {
    int col = nh * 64 + t * 16 + l15;
    float bv = bias[col];
#pragma unroll
    for (int reg = 0; reg < 4; ++reg) {
      int row = mh * 16 + quad * 4 + reg;
      h_bf[(size_t)(row0 + row) * D + col] = f2bf(acc[t][reg] + bv);
    }
  }
}

// ================= fused step: SpMM gather into LDS + gates + candidate + h update =================
// 512 threads = 8 waves per 32-row block.
// Phase A: stage h rows + gather m rows directly into sA (h | m layout).
// Phase B: each wave (mh = wave>>2, nh = wave&3) computes z AND r for its 16x32 tile;
//          z stays in registers (acc layout identical to phase-2 cand acc layout).
__global__ __launch_bounds__(512, 8) void fused_step(
    const int* __restrict__ row_start, const int2* __restrict__ edata,
    const uint4* __restrict__ h4,                         // h_in, bf16 rows (16 uint4 each)
    const short* __restrict__ packZR, const short* __restrict__ packCW,
    const float* __restrict__ ugb, const float* __restrict__ rgb,
    unsigned short* __restrict__ h_bf_out, float* __restrict__ h_f32_out, int last) {
  __shared__ __align__(16) short sA[32 * 264];            // [row][c] = [h(128) | m(128)], stride 264
  __shared__ __align__(16) short sRH[32 * 136];

  const int tid = threadIdx.x;
  const int row0 = blockIdx.x * 32;
  const int wave = tid >> 6, lane = tid & 63;
  const int sub = lane >> 4, li = lane & 15;

  // ---- Phase A1: stage this block's h rows (contiguous, coalesced) ----
  {
    int r = tid >> 4, ch = tid & 15;                      // 512 threads -> 32 rows x 16 uint4
    *(uint4*)(sA + r * 264 + ch * 8) = h4[(size_t)(row0 + r) * 16 + ch];
  }

  // ---- Phase A2: gather m for 4 rows per wave, write to sA m-half ----
  {
    const int rbase = row0 + wave * 4;
    int rs[5];
#pragma unroll
    for (int j = 0; j < 5; ++j) rs[j] = row_start[rbase + j];

    for (int i = 0; i < 4; ++i) {
      const int s0 = rs[i], end = rs[i + 1];
      float acc[8];
#pragma unroll
      for (int j = 0; j < 8; ++j) acc[j] = 0.f;

      int kk = s0;
      for (; kk + 8 <= end; kk += 8) {                    // 2 groups of 4 edges, no guards
        int2 e0 = edata[kk + sub];
        int2 e1 = edata[kk + 4 + sub];
        uint4 h0 = h4[(size_t)e0.x * 16 + li];
        uint4 h1 = h4[(size_t)e1.x * 16 + li];
        float w0 = __builtin_bit_cast(float, e0.y);
        float w1 = __builtin_bit_cast(float, e1.y);
        acc[0] += w0 * bflo(h0.x); acc[1] += w0 * bfhi(h0.x);
        acc[2] += w0 * bflo(h0.y); acc[3] += w0 * bfhi(h0.y);
        acc[4] += w0 * bflo(h0.z); acc[5] += w0 * bfhi(h0.z);
        acc[6] += w0 * bflo(h0.w); acc[7] += w0 * bfhi(h0.w);
        acc[0] += w1 * bflo(h1.x); acc[1] += w1 * bfhi(h1.x);
        acc[2] += w1 * bflo(h1.y); acc[3] += w1 * bfhi(h1.y);
        acc[4] += w1 * bflo(h1.z); acc[5] += w1 * bfhi(h1.z);
        acc[6] += w1 * bflo(h1.w); acc[7] += w1 * bfhi(h1.w);
      }
      for (; kk < end; kk += 4) {
        int e = kk + sub;
        if (e < end) {
          int2 ed = edata[e];
          uint4 hv = h4[(size_t)ed.x * 16 + li];
          float w = __builtin_bit_cast(float, ed.y);
          acc[0] += w * bflo(hv.x); acc[1] += w * bfhi(hv.x);
          acc[2] += w * bflo(hv.y); acc[3] += w * bfhi(hv.y);
          acc[4] += w * bflo(hv.z); acc[5] += w * bfhi(hv.z);
          acc[6] += w * bflo(hv.w); acc[7] += w * bfhi(hv.w);
        }
      }

      // reduce across the 4 sub-groups (lanes li, li+16, li+32, li+48 share columns)
#pragma unroll
      for (int j = 0; j < 8; ++j) acc[j] += __shfl_xor(acc[j], 16, 64);
#pragma unroll
      for (int j = 0; j < 8; ++j) acc[j] += __shfl_xor(acc[j], 32, 64);

      if (sub == 0) {
        int rl = wave * 4 + i;
        uint4 o;
        o.x = pk2(acc[0], acc[1]);
        o.y = pk2(acc[2], acc[3]);
        o.z = pk2(acc[4], acc[5]);
        o.w = pk2(acc[6], acc[7]);
        *(uint4*)(sA + rl * 264 + 128 + li * 8) = o;
      }
    }
  }
  __syncthreads();

  // ---- Phase B1: z and r gates for this wave's 16x32 tile ----
  const int quad = lane >> 4, l15 = lane & 15;
  const int mh = wave >> 2, nh = wave & 3;
  const int mrow = mh * 16 + l15;

  floatx4 accZ[2], accR[2];
  const floatx4 zero4 = {0.f, 0.f, 0.f, 0.f};
#pragma unroll
  for (int t = 0; t < 2; ++t) { accZ[t] = zero4; accR[t] = zero4; }

  const short8* pB = (const short8*)packZR;
#pragma unroll
  for (int ks = 0; ks < 8; ++ks) {
    short8 a = *(const short8*)(sA + mrow * 264 + ks * 32 + quad * 8);
#pragma unroll
    for (int t = 0; t < 2; ++t) {
      short8 bz = pB[((nh * 2 + t) * 8 + ks) * 64 + lane];
      accZ[t] = __builtin_amdgcn_mfma_f32_16x16x32_bf16(a, bz, accZ[t], 0, 0, 0);
      short8 br = pB[((8 + nh * 2 + t) * 8 + ks) * 64 + lane];
      accR[t] = __builtin_amdgcn_mfma_f32_16x16x32_bf16(a, br, accR[t], 0, 0, 0);
    }
  }

  // epilogue 1: z -> registers (overwrite accZ), rh -> sRH
#pragma unroll
  for (int t = 0; t < 2; ++t) {
    int col = nh * 32 + t * 16 + l15;
    float zb = ugb[col], rb = rgb[col];
#pragma unroll
    for (int reg = 0; reg < 4; ++reg) {
      int row = mh * 16 + quad * 4 + reg;
      float z = sig_f(accZ[t][reg] + zb);
      float rr = sig_f(accR[t][reg] + rb);
      float hv = bf2f((unsigned short)sA[row * 264 + col]);
      sRH[row * 136 + col] = (short)f2bf(rr * hv);
      accZ[t][reg] = z;
    }
  }
  __syncthreads();

  // ---- Phase B2: cand = tanh((r*h) @ CW) ----
  floatx4 acc2[2];
#pragma unroll
  for (int t = 0; t < 2; ++t) acc2[t] = zero4;

  const short8* pC = (const short8*)packCW;
#pragma unroll
  for (int ks = 0; ks < 4; ++ks) {
    short8 a = *(const short8*)(sRH + mrow * 136 + ks * 32 + quad * 8);
#pragma unroll
    for (int t = 0; t < 2; ++t) {
      short8 b = pC[((nh * 2 + t) * 4 + ks) * 64 + lane];
      acc2[t] = __builtin_amdgcn_mfma_f32_16x16x32_bf16(a, b, acc2[t], 0, 0, 0);
    }
  }

  // final: h' = z*h + (1-z)*cand   (z regs align with acc2 layout exactly)
#pragma unroll
  for (int t = 0; t < 2; ++t) {
    int col = nh * 32 + t * 16 + l15;
#pragma unroll
    for (int reg = 0; reg < 4; ++reg) {
      int row = mh * 16 + quad * 4 + reg;
      float cand = tanh_f(acc2[t][reg]);
      float z = accZ[t][reg];
      float hold = bf2f((unsigned short)sA[row * 264 + col]);
      float hn = z * hold + (1.f - z) * cand;
      size_t gi = (size_t)(row0 + row) * D + col;
      if (last) h_f32_out[gi] = hn;
      else h_bf_out[gi] = f2bf(hn);
    }
  }
}

extern "C" void kernel_launch(void* const* d_in, const int* in_sizes, int n_in,
                              void* d_out, int out_size, void* d_ws, size_t ws_size,
                              hipStream_t stream) {
  const float* input = (const float*)d_in[0];
  const int* erow    = (const int*)d_in[1];
  const int* ecol    = (const int*)d_in[2];
  const float* ew    = (const float*)d_in[3];
  const float* W     = (const float*)d_in[4];
  const float* bias  = (const float*)d_in[5];
  const float* CW    = (const float*)d_in[6];
  const float* ugW   = (const float*)d_in[7];
  const float* ugb   = (const float*)d_in[8];
  const float* rgW   = (const float*)d_in[9];
  const float* rgb   = (const float*)d_in[10];

  float* h_out = (float*)d_out;

  // ---- workspace carve-up (~78 MB) ----
  char* ws = (char*)d_ws;
  unsigned short* hA = (unsigned short*)ws;   ws += (size_t)NN * D * 2;        // 25.6 MB (h ping)
  unsigned short* hB = (unsigned short*)ws;   ws += (size_t)NN * D * 2;        // 25.6 MB (h pong)
  unsigned int* packZR = (unsigned int*)ws;   ws += 16 * 8 * 64 * 16;          // 128 KB
  unsigned int* packCW = (unsigned int*)ws;   ws += 8 * 4 * 64 * 16;           // 32 KB
  unsigned int* packW  = (unsigned int*)ws;   ws += 8 * 4 * 64 * 16;           // 32 KB
  int2* arena    = (int2*)ws;                 ws += (size_t)EE * sizeof(int2); // 12.8 MB
  int2* edata    = (int2*)ws;                 ws += (size_t)EE * sizeof(int2); // 12.8 MB
  int* cnt_pb    = (int*)ws;                  ws += SBLK * NB * sizeof(int);   // 306 KB
  int* base_pb   = (int*)ws;                  ws += SBLK * NB * sizeof(int);   // 306 KB
  int* bucket_off= (int*)ws;                  ws += (NB + 1) * sizeof(int);
  int* row_start = (int*)ws;                  ws += (NN + 1) * sizeof(int);

  // ---- CSR build (bucket multisplit) ----
  b_count<<<SBLK, 1024, 0, stream>>>(erow, cnt_pb);
  b_scan<<<1, 1024, 0, stream>>>(cnt_pb, base_pb, bucket_off);
  b_scatter<<<SBLK, 1024, 0, stream>>>(erow, ecol, ew, base_pb, arena);
  b_sort<<<NB, 256, 0, stream>>>(bucket_off, arena, edata, row_start);

  // ---- weight packing + init ----
  k_pack_zr<<<128, 64, 0, stream>>>(ugW, rgW, packZR);
  k_pack_kn<<<32, 64, 0, stream>>>(CW, packCW);
  k_pack_kn<<<32, 64, 0, stream>>>(W, packW);
  init_mfma<<<NN / 32, 256, 0, stream>>>(input, (const short*)packW, bias, hA);

  // ---- fused steps, h double-buffered (gather reads other blocks' rows) ----
  fused_step<<<NN / 32, 512, 0, stream>>>(row_start, edata, (const uint4*)hA,
                                          (const short*)packZR, (const short*)packCW,
                                          ugb, rgb, hB, h_out, 0);
  fused_step<<<NN / 32, 512, 0, stream>>>(row_start, edata, (const uint4*)hB,
                                          (const short*)packZR, (const short*)packCW,
                                          ugb, rgb, hA, h_out, 0);
  fused_step<<<NN / 32, 512, 0, stream>>>(row_start, edata, (const uint4*)hA,
                                          (const short*)packZR, (const short*)packCW,
                                          ugb, rgb, hB, h_out, 1);
}